// Round 5
// baseline (344.779 us; speedup 1.0000x reference)
//
#include <hip/hip_runtime.h>
#include <hip/hip_bf16.h>

#define B_  16
#define C_  256
#define N_  1024
#define H_  4

typedef unsigned short u16;
typedef __attribute__((ext_vector_type(8))) short bf16x8;
typedef __attribute__((ext_vector_type(4))) float f32x4;

__device__ __forceinline__ u16 f2bf(float f) {
    union { float f; unsigned u; } v; v.f = f;
    unsigned r = v.u + 0x7FFFu + ((v.u >> 16) & 1u);
    return (u16)(r >> 16);
}
__device__ __forceinline__ float bf2f(u16 h) {
    union { unsigned u; float f; } v; v.u = ((unsigned)h) << 16;
    return v.f;
}
__device__ __forceinline__ unsigned pack2bf(float a, float b) {
    __hip_bfloat162 h = __float22bfloat162_rn(make_float2(a, b));
    union { __hip_bfloat162 h2; unsigned u; } cv; cv.h2 = h;
    return cv.u;
}

// ---- all 5 weight matrices f32 -> bf16 arena: wq|wkv|wlq|wproj|wlkv ----
__global__ __launch_bounds__(256) void k_f2bf5(const float* __restrict__ a0,
                                               const float* __restrict__ a1,
                                               const float* __restrict__ a2,
                                               const float* __restrict__ a3,
                                               const float* __restrict__ a4,
                                               u16* __restrict__ dst) {
    int i = blockIdx.x * 256 + threadIdx.x;  // float4 index, total 114688
    const float* s; int off;
    if (i < 16384)      { s = a0; off = 0; }
    else if (i < 49152) { s = a1; off = 16384; }
    else if (i < 65536) { s = a2; off = 49152; }
    else if (i < 81920) { s = a3; off = 65536; }
    else                { s = a4; off = 81920; }
    float4 v = reinterpret_cast<const float4*>(s)[i - off];
    ushort4 o;
    o.x = f2bf(v.x); o.y = f2bf(v.y); o.z = f2bf(v.z); o.w = f2bf(v.w);
    reinterpret_cast<ushort4*>(dst)[i] = o;
}

// ---------------- x[b][c][n] f32 -> xf[b][n][c] bf16 ----------------
__global__ __launch_bounds__(256) void k_transpose_x(const float* __restrict__ x,
                                                     u16* __restrict__ xf) {
    __shared__ u16 tile[32][33];
    int b = blockIdx.z;
    int n0 = blockIdx.x * 32, c0 = blockIdx.y * 32;
    int tx = threadIdx.x, ty = threadIdx.y;  // 32 x 8
#pragma unroll
    for (int i = 0; i < 4; i++)
        tile[ty + i * 8][tx] =
            f2bf(x[((size_t)(b * C_ + c0 + ty + i * 8)) * N_ + n0 + tx]);
    __syncthreads();
#pragma unroll
    for (int i = 0; i < 4; i++)
        xf[((size_t)(b * N_ + n0 + ty + i * 8)) * C_ + c0 + tx] = tile[tx][ty + i * 8];
}

// ---- V rows of src[b][n][stride] -> Vt[b][h][d][n~] with kv-permutation pi ----
// column npos holds kv row n where npos = (n&~63)|((n&15)*4 + ((n>>4)&3))
__global__ __launch_bounds__(256) void k_transposeV(const u16* __restrict__ src,
                                                    int stride,
                                                    u16* __restrict__ Vt) {
    __shared__ u16 tile[32][33];
    int b = blockIdx.z;
    int n0 = blockIdx.x * 32, vc0 = blockIdx.y * 32;  // vc0 in [0,256)
    int h = vc0 >> 6, dl = vc0 & 63;
    int tx = threadIdx.x, ty = threadIdx.y;
#pragma unroll
    for (int i = 0; i < 4; i++)
        tile[ty + i * 8][tx] =
            src[((size_t)(b * N_ + n0 + ty + i * 8)) * stride + vc0 + tx];
    __syncthreads();
    int n = n0 + tx;
    int npos = (n & ~63) | (((n & 15) << 2) | ((n >> 4) & 3));
#pragma unroll
    for (int i = 0; i < 4; i++)
        Vt[((size_t)((b * H_ + h) * 64 + dl + ty + i * 8)) * N_ + npos] =
            tile[tx][ty + i * 8];
}

// ---------------- MFMA GEMM: C[m][n] = A[m][:] . W[n][:] (+bias from bofs) ----
__global__ __launch_bounds__(256) void k_gemm_bf16(const u16* __restrict__ A,
                                                   const u16* __restrict__ W,
                                                   const float* __restrict__ bias,
                                                   int bofs, u16* __restrict__ C,
                                                   int Nout, int ldc) {
    __shared__ u16 As[128][40];
    __shared__ u16 Bs[128][40];
    int m0 = blockIdx.y * 128, n0 = blockIdx.x * 128;
    int t = threadIdx.x;
    int wid = t >> 6, lane = t & 63;
    int l16 = lane & 15, g = lane >> 4;
    int wm = (wid >> 1) * 64, wn = (wid & 1) * 64;
    int srow = t >> 1, scol = (t & 1) * 16;
    f32x4 zz = {0.f, 0.f, 0.f, 0.f};
    f32x4 acc[4][4];
#pragma unroll
    for (int i = 0; i < 4; i++)
#pragma unroll
        for (int j = 0; j < 4; j++) acc[i][j] = zz;
    for (int k0 = 0; k0 < 256; k0 += 32) {
        __syncthreads();
        const u16* a_src = A + (size_t)(m0 + srow) * 256 + k0 + scol;
        const u16* w_src = W + (size_t)(n0 + srow) * 256 + k0 + scol;
        *reinterpret_cast<bf16x8*>(&As[srow][scol]) =
            *reinterpret_cast<const bf16x8*>(a_src);
        *reinterpret_cast<bf16x8*>(&As[srow][scol + 8]) =
            *reinterpret_cast<const bf16x8*>(a_src + 8);
        *reinterpret_cast<bf16x8*>(&Bs[srow][scol]) =
            *reinterpret_cast<const bf16x8*>(w_src);
        *reinterpret_cast<bf16x8*>(&Bs[srow][scol + 8]) =
            *reinterpret_cast<const bf16x8*>(w_src + 8);
        __syncthreads();
        bf16x8 af[4], bfr[4];
#pragma unroll
        for (int mt = 0; mt < 4; mt++)
            af[mt] = *reinterpret_cast<const bf16x8*>(&As[wm + mt * 16 + l16][g * 8]);
#pragma unroll
        for (int nt = 0; nt < 4; nt++)
            bfr[nt] = *reinterpret_cast<const bf16x8*>(&Bs[wn + nt * 16 + l16][g * 8]);
#pragma unroll
        for (int mt = 0; mt < 4; mt++)
#pragma unroll
            for (int nt = 0; nt < 4; nt++)
                acc[mt][nt] = __builtin_amdgcn_mfma_f32_16x16x32_bf16(
                    af[mt], bfr[nt], acc[mt][nt], 0, 0, 0);
    }
    float bval[4];
#pragma unroll
    for (int nt = 0; nt < 4; nt++) {
        int n = n0 + wn + nt * 16 + l16;
        bval[nt] = (bias && n >= bofs) ? bias[n - bofs] : 0.0f;
    }
#pragma unroll
    for (int mt = 0; mt < 4; mt++)
#pragma unroll
        for (int r = 0; r < 4; r++) {
            int m = m0 + wm + mt * 16 + g * 4 + r;
#pragma unroll
            for (int nt = 0; nt < 4; nt++) {
                int n = n0 + wn + nt * 16 + l16;
                C[(size_t)m * ldc + n] = f2bf(acc[mt][nt][r] + bval[nt]);
            }
        }
}

// ---------------- depthwise 3x3 conv + bias + residual (bf16 io) ----------------
__global__ __launch_bounds__(256) void k_dwconv_add(const u16* __restrict__ yp,
                                                    const float* __restrict__ dw_w,
                                                    const float* __restrict__ dw_b,
                                                    u16* __restrict__ out) {
    int b = blockIdx.y;
    int n = blockIdx.x;
    int cc = threadIdx.x;
    int yy = n >> 5, xx = n & 31;
    const u16* ypb = yp + (size_t)b * N_ * C_;
    float acc = dw_b[cc];
#pragma unroll
    for (int dy = 0; dy < 3; dy++) {
        int y2 = yy + dy - 1;
        if (y2 < 0 || y2 >= 32) continue;
#pragma unroll
        for (int dx = 0; dx < 3; dx++) {
            int x2 = xx + dx - 1;
            if (x2 < 0 || x2 >= 32) continue;
            acc += bf2f(ypb[(size_t)(y2 * 32 + x2) * C_ + cc]) * dw_w[cc * 9 + dy * 3 + dx];
        }
    }
    out[(size_t)b * N_ * C_ + (size_t)n * C_ + cc] =
        f2bf(acc + bf2f(ypb[(size_t)n * C_ + cc]));
}

// ---------------- MFMA flash attention, no-max softmax, L2-direct K/V ----------
// K/V fragments read straight from global (L2-resident thanks to XCD swizzle).
// No barriers in the main loop; only per-wave P goes through LDS.
// Q rows stride qstr (head col h*64); K rows stride kstr (head col h*64);
// Vt: [b][h][64 d][N kv-permuted].  4 waves x 16 q-rows, KV tiles of 64.
template <int STAGE>
__global__ __launch_bounds__(256) void k_attn_mfma(const u16* __restrict__ Q, int qstr,
                                                   const u16* __restrict__ K, int kstr,
                                                   const u16* __restrict__ Vt,
                                                   void* __restrict__ outp) {
    __shared__ union SMem { u16 Ps[4][16][72]; float Os[64][68]; } sm;

    int cid = blockIdx.x;
    int xcd = cid & 7, slot = cid >> 3;
    int qt = slot & 15, ghi = slot >> 4;
    int grp = ghi * 8 + xcd;           // 64 (h,b) groups, 8 per XCD
    int h = grp & 3, b = grp >> 2;
    int q0 = qt * 64;
    int t = threadIdx.x;
    int wid = t >> 6, lane = t & 63;
    int l16 = lane & 15, g = lane >> 4, g8 = g * 8;

    // Q fragments, prescaled by 1/8 (exponent shift -> exact in bf16)
    const u16* Qrow = Q + ((size_t)(b * N_ + q0 + wid * 16 + l16)) * qstr + h * 64;
    bf16x8 qf[2];
    qf[0] = *reinterpret_cast<const bf16x8*>(Qrow + g8);
    qf[1] = *reinterpret_cast<const bf16x8*>(Qrow + 32 + g8);
#pragma unroll
    for (int w = 0; w < 2; w++)
#pragma unroll
        for (int j = 0; j < 8; j++)
            qf[w][j] = (short)f2bf(bf2f((u16)qf[w][j]) * 0.125f);

    // per-lane fragment base pointers (L2-hit reads, no LDS staging)
    const u16* Kbase = K + ((size_t)(b * N_ + l16)) * kstr + h * 64 + g8;
    const u16* Vbase = Vt + ((size_t)((b * H_ + h) * 64 + l16)) * N_ + g8;

    f32x4 zz = {0.f, 0.f, 0.f, 0.f};
    f32x4 accO[4];
#pragma unroll
    for (int dt = 0; dt < 4; dt++) accO[dt] = zz;
    float lsum[4] = {0.f, 0.f, 0.f, 0.f};

    for (int kb = 0; kb < 16; kb++) {
        // S = Q . K^T  — K fragments direct from global
        f32x4 s4[4];
#pragma unroll
        for (int nt = 0; nt < 4; nt++) s4[nt] = zz;
#pragma unroll
        for (int nt = 0; nt < 4; nt++) {
            const u16* kp = Kbase + (size_t)(kb * 64 + nt * 16) * kstr;
            bf16x8 kf0 = *reinterpret_cast<const bf16x8*>(kp);
            bf16x8 kf1 = *reinterpret_cast<const bf16x8*>(kp + 32);
            s4[nt] = __builtin_amdgcn_mfma_f32_16x16x32_bf16(qf[0], kf0, s4[nt], 0, 0, 0);
            s4[nt] = __builtin_amdgcn_mfma_f32_16x16x32_bf16(qf[1], kf1, s4[nt], 0, 0, 0);
        }
        // p = exp(S) (no max: |S| < ~1 by construction; softmax shift-invariant)
#pragma unroll
        for (int r = 0; r < 4; r++) {
            float p0 = __expf(s4[0][r]);
            float p1 = __expf(s4[1][r]);
            float p2 = __expf(s4[2][r]);
            float p3 = __expf(s4[3][r]);
            lsum[r] += (p0 + p1) + (p2 + p3);
            uint2 pw;
            pw.x = pack2bf(p0, p1);
            pw.y = pack2bf(p2, p3);
            // kv-permuted col: kv=nt*16+l16 stored at col l16*4+nt (matches Vt pi)
            *reinterpret_cast<uint2*>(&sm.Ps[wid][g * 4 + r][l16 * 4]) = pw;
        }
        // O += P . V  — V fragments direct from global (Vt is kv-permuted)
#pragma unroll
        for (int kc = 0; kc < 2; kc++) {
            bf16x8 pf = *reinterpret_cast<const bf16x8*>(&sm.Ps[wid][l16][kc * 32 + g8]);
#pragma unroll
            for (int dt = 0; dt < 4; dt++) {
                bf16x8 vf = *reinterpret_cast<const bf16x8*>(
                    Vbase + (size_t)(dt * 16) * N_ + kb * 64 + kc * 32);
                accO[dt] = __builtin_amdgcn_mfma_f32_16x16x32_bf16(pf, vf, accO[dt], 0, 0, 0);
            }
        }
    }
    // single deferred row-sum reduce (within 16-lane groups)
    float inv[4];
#pragma unroll
    for (int r = 0; r < 4; r++) {
        float l = lsum[r];
        l += __shfl_xor(l, 1);
        l += __shfl_xor(l, 2);
        l += __shfl_xor(l, 4);
        l += __shfl_xor(l, 8);
        inv[r] = 1.0f / l;
    }

    if (STAGE == 0) {
        u16* O = (u16*)outp;
#pragma unroll
        for (int dt = 0; dt < 4; dt++)
#pragma unroll
            for (int r = 0; r < 4; r++)
                O[((size_t)(b * N_ + q0 + wid * 16 + g * 4 + r)) * C_ + h * 64 +
                  dt * 16 + l16] = f2bf(accO[dt][r] * inv[r]);
    } else {
        __syncthreads();  // all waves done with Ps before union reuse
#pragma unroll
        for (int dt = 0; dt < 4; dt++)
#pragma unroll
            for (int r = 0; r < 4; r++)
                sm.Os[wid * 16 + g * 4 + r][dt * 16 + l16] = accO[dt][r] * inv[r];
        __syncthreads();
        // batch-mixing scatter: bo=(n&1)*8+h*2+(b>>3), co=((n>>1)&3)*64+d,
        // no=(b&7)*128+(n>>3); 8 consecutive no per 32B segment
        float* out = (float*)outp;
#pragma unroll
        for (int e = 0; e < 2; e++) {
            int seg = t + e * 256;
            int d = seg & 63, tb = seg >> 6;
            int tl = tb & 1, q2 = tb >> 1;
            int bo = tl * 8 + h * 2 + (b >> 3);
            int co = q2 * 64 + d;
            size_t base = (size_t)bo * (C_ * N_) + (size_t)co * N_ + (b & 7) * 128 + (q0 >> 3);
            float4 v0, v1;
            v0.x = sm.Os[0 * 8 + q2 * 2 + tl][d];
            v0.y = sm.Os[1 * 8 + q2 * 2 + tl][d];
            v0.z = sm.Os[2 * 8 + q2 * 2 + tl][d];
            v0.w = sm.Os[3 * 8 + q2 * 2 + tl][d];
            v1.x = sm.Os[4 * 8 + q2 * 2 + tl][d];
            v1.y = sm.Os[5 * 8 + q2 * 2 + tl][d];
            v1.z = sm.Os[6 * 8 + q2 * 2 + tl][d];
            v1.w = sm.Os[7 * 8 + q2 * 2 + tl][d];
            *reinterpret_cast<float4*>(&out[base]) = v0;
            *reinterpret_cast<float4*>(&out[base + 4]) = v1;
        }
    }
}

extern "C" void kernel_launch(void* const* d_in, const int* in_sizes, int n_in,
                              void* d_out, int out_size, void* d_ws, size_t ws_size,
                              hipStream_t stream) {
    const float* x      = (const float*)d_in[0];
    const float* q_w    = (const float*)d_in[1];
    const float* kv_w   = (const float*)d_in[2];
    const float* proj_w = (const float*)d_in[3];
    const float* proj_b = (const float*)d_in[4];
    const float* lq_w   = (const float*)d_in[5];
    const float* lq_b   = (const float*)d_in[6];
    const float* lkv_w  = (const float*)d_in[7];
    const float* lkv_b  = (const float*)d_in[8];
    // d_in[9] = rel_bias: constant along softmax axis -> exact no-op
    const float* dw_w   = (const float*)d_in[10];
    const float* dw_b   = (const float*)d_in[11];

    const size_t SZ = (size_t)B_ * N_ * C_;  // 4M elems
    u16* ws = (u16*)d_ws;
    u16* xf    = ws;             // [0,SZ): xf -> yb -> s2in
    u16* qkv   = ws + SZ;        // [SZ,5SZ): cols 0..255 q | 256..767 kv/kv2 | 768..1023 q2
    u16* Vt    = ws + 5 * SZ;    // [5SZ,6SZ): Vt -> ypb -> Vt2
    u16* arena = ws + 6 * SZ;    // weights: wq|wkv|wlq|wproj|wlkv
    u16* wfused = arena;                 // [1024][256]
    u16* wproj  = arena + 262144;
    u16* wlkv   = arena + 327680;

    k_f2bf5<<<448, 256, 0, stream>>>(q_w, kv_w, lq_w, proj_w, lkv_w, arena);
    k_transpose_x<<<dim3(32, 8, B_), dim3(32, 8), 0, stream>>>(x, xf);
    // fused q|kv|q2 projections
    k_gemm_bf16<<<dim3(8, 128), 256, 0, stream>>>(xf, wfused, lq_b, 768, qkv, 1024, 1024);
    k_transposeV<<<dim3(32, 8, B_), dim3(32, 8), 0, stream>>>(qkv + 512, 1024, Vt);
    k_attn_mfma<0><<<1024, 256, 0, stream>>>(qkv, 1024, qkv + 256, 1024, Vt, xf /*yb*/);
    k_gemm_bf16<<<dim3(2, 128), 256, 0, stream>>>(xf /*yb*/, wproj, proj_b, 0,
                                                  Vt /*ypb*/, 256, 256);
    k_dwconv_add<<<dim3(N_, B_), 256, 0, stream>>>(Vt /*ypb*/, dw_w, dw_b, xf /*s2in*/);
    k_gemm_bf16<<<dim3(4, 128), 256, 0, stream>>>(xf /*s2in*/, wlkv, lkv_b, 0,
                                                  qkv + 256, 512, 1024);
    k_transposeV<<<dim3(32, 8, B_), dim3(32, 8), 0, stream>>>(qkv + 512, 1024, Vt /*Vt2*/);
    k_attn_mfma<1><<<1024, 256, 0, stream>>>(qkv + 768, 1024, qkv + 256, 1024, Vt, d_out);
}

// Round 6
// 229.978 us; speedup vs baseline: 1.4992x; 1.4992x over previous
//
#include <hip/hip_runtime.h>
#include <hip/hip_bf16.h>

#define B_  16
#define C_  256
#define N_  1024
#define H_  4

typedef unsigned short u16;
typedef __attribute__((ext_vector_type(8))) short bf16x8;
typedef __attribute__((ext_vector_type(4))) float f32x4;

#if __has_builtin(__builtin_amdgcn_exp2f)
#define EXP2(x) __builtin_amdgcn_exp2f(x)
#else
#define EXP2(x) __builtin_exp2f(x)
#endif

__device__ __forceinline__ u16 f2bf(float f) {
    union { float f; unsigned u; } v; v.f = f;
    unsigned r = v.u + 0x7FFFu + ((v.u >> 16) & 1u);
    return (u16)(r >> 16);
}
__device__ __forceinline__ float bf2f(u16 h) {
    union { unsigned u; float f; } v; v.u = ((unsigned)h) << 16;
    return v.f;
}
__device__ __forceinline__ unsigned pack2bf(float a, float b) {
    __hip_bfloat162 h = __float22bfloat162_rn(make_float2(a, b));
    union { __hip_bfloat162 h2; unsigned u; } cv; cv.h2 = h;
    return cv.u;
}

// ---- all 5 weight matrices f32 -> bf16 arena: wq|wkv|wlq|wproj|wlkv ----
__global__ __launch_bounds__(256) void k_f2bf5(const float* __restrict__ a0,
                                               const float* __restrict__ a1,
                                               const float* __restrict__ a2,
                                               const float* __restrict__ a3,
                                               const float* __restrict__ a4,
                                               u16* __restrict__ dst) {
    int i = blockIdx.x * 256 + threadIdx.x;  // float4 index, total 114688
    const float* s; int off;
    if (i < 16384)      { s = a0; off = 0; }
    else if (i < 49152) { s = a1; off = 16384; }
    else if (i < 65536) { s = a2; off = 49152; }
    else if (i < 81920) { s = a3; off = 65536; }
    else                { s = a4; off = 81920; }
    float4 v = reinterpret_cast<const float4*>(s)[i - off];
    ushort4 o;
    o.x = f2bf(v.x); o.y = f2bf(v.y); o.z = f2bf(v.z); o.w = f2bf(v.w);
    reinterpret_cast<ushort4*>(dst)[i] = o;
}

// ---------------- x[b][c][n] f32 -> xf[b][n][c] bf16 ----------------
__global__ __launch_bounds__(256) void k_transpose_x(const float* __restrict__ x,
                                                     u16* __restrict__ xf) {
    __shared__ u16 tile[32][33];
    int b = blockIdx.z;
    int n0 = blockIdx.x * 32, c0 = blockIdx.y * 32;
    int tx = threadIdx.x, ty = threadIdx.y;  // 32 x 8
#pragma unroll
    for (int i = 0; i < 4; i++)
        tile[ty + i * 8][tx] =
            f2bf(x[((size_t)(b * C_ + c0 + ty + i * 8)) * N_ + n0 + tx]);
    __syncthreads();
#pragma unroll
    for (int i = 0; i < 4; i++)
        xf[((size_t)(b * N_ + n0 + ty + i * 8)) * C_ + c0 + tx] = tile[tx][ty + i * 8];
}

// ---- V rows of src[b][n][stride] -> Vt[b][h][d][n] (plain transpose) ----
__global__ __launch_bounds__(256) void k_transposeV(const u16* __restrict__ src,
                                                    int stride,
                                                    u16* __restrict__ Vt) {
    __shared__ u16 tile[32][33];
    int b = blockIdx.z;
    int n0 = blockIdx.x * 32, vc0 = blockIdx.y * 32;  // vc0 in [0,256)
    int h = vc0 >> 6, dl = vc0 & 63;
    int tx = threadIdx.x, ty = threadIdx.y;
#pragma unroll
    for (int i = 0; i < 4; i++)
        tile[ty + i * 8][tx] =
            src[((size_t)(b * N_ + n0 + ty + i * 8)) * stride + vc0 + tx];
    __syncthreads();
#pragma unroll
    for (int i = 0; i < 4; i++)
        Vt[((size_t)((b * H_ + h) * 64 + dl + ty + i * 8)) * N_ + n0 + tx] =
            tile[tx][ty + i * 8];
}

// ---------------- MFMA GEMM: C[m][n] = A[m][:] . W[n][:] (+bias from bofs) ----
__global__ __launch_bounds__(256) void k_gemm_bf16(const u16* __restrict__ A,
                                                   const u16* __restrict__ W,
                                                   const float* __restrict__ bias,
                                                   int bofs, u16* __restrict__ C,
                                                   int Nout, int ldc) {
    __shared__ u16 As[128][40];
    __shared__ u16 Bs[128][40];
    int m0 = blockIdx.y * 128, n0 = blockIdx.x * 128;
    int t = threadIdx.x;
    int wid = t >> 6, lane = t & 63;
    int l16 = lane & 15, g = lane >> 4;
    int wm = (wid >> 1) * 64, wn = (wid & 1) * 64;
    int srow = t >> 1, scol = (t & 1) * 16;
    f32x4 zz = {0.f, 0.f, 0.f, 0.f};
    f32x4 acc[4][4];
#pragma unroll
    for (int i = 0; i < 4; i++)
#pragma unroll
        for (int j = 0; j < 4; j++) acc[i][j] = zz;
    for (int k0 = 0; k0 < 256; k0 += 32) {
        __syncthreads();
        const u16* a_src = A + (size_t)(m0 + srow) * 256 + k0 + scol;
        const u16* w_src = W + (size_t)(n0 + srow) * 256 + k0 + scol;
        *reinterpret_cast<bf16x8*>(&As[srow][scol]) =
            *reinterpret_cast<const bf16x8*>(a_src);
        *reinterpret_cast<bf16x8*>(&As[srow][scol + 8]) =
            *reinterpret_cast<const bf16x8*>(a_src + 8);
        *reinterpret_cast<bf16x8*>(&Bs[srow][scol]) =
            *reinterpret_cast<const bf16x8*>(w_src);
        *reinterpret_cast<bf16x8*>(&Bs[srow][scol + 8]) =
            *reinterpret_cast<const bf16x8*>(w_src + 8);
        __syncthreads();
        bf16x8 af[4], bfr[4];
#pragma unroll
        for (int mt = 0; mt < 4; mt++)
            af[mt] = *reinterpret_cast<const bf16x8*>(&As[wm + mt * 16 + l16][g * 8]);
#pragma unroll
        for (int nt = 0; nt < 4; nt++)
            bfr[nt] = *reinterpret_cast<const bf16x8*>(&Bs[wn + nt * 16 + l16][g * 8]);
#pragma unroll
        for (int mt = 0; mt < 4; mt++)
#pragma unroll
            for (int nt = 0; nt < 4; nt++)
                acc[mt][nt] = __builtin_amdgcn_mfma_f32_16x16x32_bf16(
                    af[mt], bfr[nt], acc[mt][nt], 0, 0, 0);
    }
    float bval[4];
#pragma unroll
    for (int nt = 0; nt < 4; nt++) {
        int n = n0 + wn + nt * 16 + l16;
        bval[nt] = (bias && n >= bofs) ? bias[n - bofs] : 0.0f;
    }
#pragma unroll
    for (int mt = 0; mt < 4; mt++)
#pragma unroll
        for (int r = 0; r < 4; r++) {
            int m = m0 + wm + mt * 16 + g * 4 + r;
#pragma unroll
            for (int nt = 0; nt < 4; nt++) {
                int n = n0 + wn + nt * 16 + l16;
                C[(size_t)m * ldc + n] = f2bf(acc[mt][nt][r] + bval[nt]);
            }
        }
}

// ---------------- depthwise 3x3 conv + bias + residual (bf16 io) ----------------
__global__ __launch_bounds__(256) void k_dwconv_add(const u16* __restrict__ yp,
                                                    const float* __restrict__ dw_w,
                                                    const float* __restrict__ dw_b,
                                                    u16* __restrict__ out) {
    int b = blockIdx.y;
    int n = blockIdx.x;
    int cc = threadIdx.x;
    int yy = n >> 5, xx = n & 31;
    const u16* ypb = yp + (size_t)b * N_ * C_;
    float acc = dw_b[cc];
#pragma unroll
    for (int dy = 0; dy < 3; dy++) {
        int y2 = yy + dy - 1;
        if (y2 < 0 || y2 >= 32) continue;
#pragma unroll
        for (int dx = 0; dx < 3; dx++) {
            int x2 = xx + dx - 1;
            if (x2 < 0 || x2 >= 32) continue;
            acc += bf2f(ypb[(size_t)(y2 * 32 + x2) * C_ + cc]) * dw_w[cc * 9 + dy * 3 + dx];
        }
    }
    out[(size_t)b * N_ * C_ + (size_t)n * C_ + cc] =
        f2bf(acc + bf2f(ypb[(size_t)n * C_ + cc]));
}

// ---------------- MFMA flash attention: all-register P (swapped layout) -------
// S^T = mfma(A=K_perm, B=Q); K rows permuted so S^T frag rows == PV B-frag kv
// order. O^T = mfma(A=V^T, B=P^T) with P^T taken directly from registers.
// No LDS / barriers / shuffles in the main loop. 4 waves x 32 q-rows per block.
// Grid: 512 blocks XCD-swizzled (8 KV panels per XCD -> L2-resident).
template <int STAGE>
__global__ __launch_bounds__(256) void k_attn_mfma(const u16* __restrict__ Q, int qstr,
                                                   const u16* __restrict__ K, int kstr,
                                                   const u16* __restrict__ Vt,
                                                   void* __restrict__ outp) {
    int cid = blockIdx.x;
    int xcd = cid & 7, slot = cid >> 3;
    int bh = xcd * 8 + (slot & 7);   // 64 (b,h) panels, 8 per XCD
    int qc = slot >> 3;              // q-chunk 0..7 (128 rows each)
    int h = bh & 3, b = bh >> 2;
    int t = threadIdx.x;
    int wv = t >> 6, lane = t & 63;
    int l16 = lane & 15, g = lane >> 4, g8 = g * 8;
    // K-row permutation: frag row rho=l16 loads kv offset rperm within 8-stripes
    int rperm = ((l16 & 12) << 1) | (l16 & 3);

    // Q fragments (B-operand layout == natural row-major frag), prescaled by
    // 0.125*log2(e) so softmax is exp2(S) with a single v_exp each.
    const float SCL = 0.18033688011112042f;
    const u16* Qb = Q + ((size_t)(b * N_ + qc * 128 + wv * 32 + l16)) * qstr + h * 64 + g8;
    bf16x8 qf[2][2];
#pragma unroll
    for (int qg = 0; qg < 2; qg++)
#pragma unroll
        for (int w2 = 0; w2 < 2; w2++) {
            qf[qg][w2] = *reinterpret_cast<const bf16x8*>(Qb + qg * 16 * qstr + w2 * 32);
#pragma unroll
            for (int j = 0; j < 8; j++)
                qf[qg][w2][j] = (short)f2bf(bf2f((u16)qf[qg][w2][j]) * SCL);
        }

    const u16* Kb2 = K + ((size_t)(b * N_) + rperm) * kstr + h * 64 + g8;
    const u16* Vb  = Vt + ((size_t)(bh * 64 + l16)) * N_ + g8;

    // prologue: K fragments for kb=0
    bf16x8 kf[4][2];
#pragma unroll
    for (int nt = 0; nt < 4; nt++)
#pragma unroll
        for (int w2 = 0; w2 < 2; w2++)
            kf[nt][w2] = *reinterpret_cast<const bf16x8*>(
                Kb2 + (size_t)((nt >> 1) * 32 + (nt & 1) * 4) * kstr + w2 * 32);

    f32x4 zz = {0.f, 0.f, 0.f, 0.f};
    f32x4 accO[4][2];  // [dt][qg], holds O^T[d=dt*16+g*4+r][q=qg*16+l16]
#pragma unroll
    for (int dt = 0; dt < 4; dt++)
#pragma unroll
        for (int qg = 0; qg < 2; qg++) accO[dt][qg] = zz;
    float lsum[2] = {0.f, 0.f};
    int pwv[2][8];  // packed bf16 P pairs, [qg][nt*2+m]

    for (int kb = 0; kb < 16; kb++) {
        // V fragments for this tile (used ~after QK+exp -> latency hidden)
        bf16x8 vf[2][4];
#pragma unroll
        for (int kc = 0; kc < 2; kc++)
#pragma unroll
            for (int dt = 0; dt < 4; dt++)
                vf[kc][dt] = *reinterpret_cast<const bf16x8*>(
                    Vb + (size_t)(dt * 16) * N_ + kb * 64 + kc * 32);
        // S^T = K_perm . Q  ; then p = exp2(S) all in registers
#pragma unroll
        for (int qg = 0; qg < 2; qg++) {
            f32x4 st[4];
#pragma unroll
            for (int nt = 0; nt < 4; nt++) st[nt] = zz;
#pragma unroll
            for (int nt = 0; nt < 4; nt++) {
                st[nt] = __builtin_amdgcn_mfma_f32_16x16x32_bf16(kf[nt][0], qf[qg][0],
                                                                 st[nt], 0, 0, 0);
                st[nt] = __builtin_amdgcn_mfma_f32_16x16x32_bf16(kf[nt][1], qf[qg][1],
                                                                 st[nt], 0, 0, 0);
            }
#pragma unroll
            for (int nt = 0; nt < 4; nt++) {
                float p0 = EXP2(st[nt][0]);
                float p1 = EXP2(st[nt][1]);
                float p2 = EXP2(st[nt][2]);
                float p3 = EXP2(st[nt][3]);
                lsum[qg] += (p0 + p1) + (p2 + p3);
                pwv[qg][nt * 2 + 0] = (int)pack2bf(p0, p1);
                pwv[qg][nt * 2 + 1] = (int)pack2bf(p2, p3);
            }
        }
        // prefetch next K tile into the (now dead) kf regs
        {
            int nkb = (kb < 15) ? kb + 1 : 15;
            const u16* Kt = Kb2 + (size_t)(nkb * 64) * kstr;
#pragma unroll
            for (int nt = 0; nt < 4; nt++)
#pragma unroll
                for (int w2 = 0; w2 < 2; w2++)
                    kf[nt][w2] = *reinterpret_cast<const bf16x8*>(
                        Kt + (size_t)((nt >> 1) * 32 + (nt & 1) * 4) * kstr + w2 * 32);
        }
        // O^T += V^T . P^T  (P^T B-frags are the lane's own pwv words)
#pragma unroll
        for (int qg = 0; qg < 2; qg++)
#pragma unroll
            for (int kc = 0; kc < 2; kc++) {
                union { int i[4]; bf16x8 v; } u;
                u.i[0] = pwv[qg][4 * kc + 0];
                u.i[1] = pwv[qg][4 * kc + 1];
                u.i[2] = pwv[qg][4 * kc + 2];
                u.i[3] = pwv[qg][4 * kc + 3];
#pragma unroll
                for (int dt = 0; dt < 4; dt++)
                    accO[dt][qg] = __builtin_amdgcn_mfma_f32_16x16x32_bf16(
                        vf[kc][dt], u.v, accO[dt][qg], 0, 0, 0);
            }
    }
    // row-sum: lane holds disjoint kv-quarters -> reduce across g (bits 4,5)
    float inv[2];
#pragma unroll
    for (int qg = 0; qg < 2; qg++) {
        float l = lsum[qg];
        l += __shfl_xor(l, 16);
        l += __shfl_xor(l, 32);
        inv[qg] = 1.0f / l;
    }

    if constexpr (STAGE == 0) {
        u16* O = (u16*)outp;
        size_t rowb = (size_t)(b * N_ + qc * 128 + wv * 32 + l16);
#pragma unroll
        for (int qg = 0; qg < 2; qg++)
#pragma unroll
            for (int dt = 0; dt < 4; dt++) {
                ushort4 o;
                o.x = f2bf(accO[dt][qg][0] * inv[qg]);
                o.y = f2bf(accO[dt][qg][1] * inv[qg]);
                o.z = f2bf(accO[dt][qg][2] * inv[qg]);
                o.w = f2bf(accO[dt][qg][3] * inv[qg]);
                *reinterpret_cast<ushort4*>(
                    &O[(rowb + qg * 16) * C_ + h * 64 + dt * 16 + g * 4]) = o;
            }
    } else {
        __shared__ float Os[128][68];
        int qrl = wv * 32 + l16;
#pragma unroll
        for (int qg = 0; qg < 2; qg++)
#pragma unroll
            for (int dt = 0; dt < 4; dt++)
#pragma unroll
                for (int r = 0; r < 4; r++)
                    Os[qrl + qg * 16][dt * 16 + g * 4 + r] = accO[dt][qg][r] * inv[qg];
        __syncthreads();
        // batch-mixing scatter: bo=(n&1)*8+h*2+(b>>3), co=((n>>1)&3)*64+d,
        // no=(b&7)*128+(n>>3); 16 consecutive no per (tl,q2,d) row
        float* out = (float*)outp;
#pragma unroll
        for (int e = 0; e < 2; e++) {
            int seg = t + e * 256;
            int d = seg & 63, tb = seg >> 6;
            int tl = tb & 1, q2 = tb >> 1;
            int bo = tl * 8 + h * 2 + (b >> 3);
            int co = q2 * 64 + d;
            size_t base = (size_t)bo * (C_ * N_) + (size_t)co * N_ + (b & 7) * 128 + qc * 16;
#pragma unroll
            for (int k4 = 0; k4 < 4; k4++) {
                float4 v;
                v.x = Os[(k4 * 4 + 0) * 8 + q2 * 2 + tl][d];
                v.y = Os[(k4 * 4 + 1) * 8 + q2 * 2 + tl][d];
                v.z = Os[(k4 * 4 + 2) * 8 + q2 * 2 + tl][d];
                v.w = Os[(k4 * 4 + 3) * 8 + q2 * 2 + tl][d];
                *reinterpret_cast<float4*>(&out[base + k4 * 4]) = v;
            }
        }
    }
}

extern "C" void kernel_launch(void* const* d_in, const int* in_sizes, int n_in,
                              void* d_out, int out_size, void* d_ws, size_t ws_size,
                              hipStream_t stream) {
    const float* x      = (const float*)d_in[0];
    const float* q_w    = (const float*)d_in[1];
    const float* kv_w   = (const float*)d_in[2];
    const float* proj_w = (const float*)d_in[3];
    const float* proj_b = (const float*)d_in[4];
    const float* lq_w   = (const float*)d_in[5];
    const float* lq_b   = (const float*)d_in[6];
    const float* lkv_w  = (const float*)d_in[7];
    const float* lkv_b  = (const float*)d_in[8];
    // d_in[9] = rel_bias: constant along softmax axis -> exact no-op
    const float* dw_w   = (const float*)d_in[10];
    const float* dw_b   = (const float*)d_in[11];

    const size_t SZ = (size_t)B_ * N_ * C_;  // 4M elems
    u16* ws = (u16*)d_ws;
    u16* xf    = ws;             // [0,SZ): xf -> yb -> s2in -> Vt2
    u16* qkv   = ws + SZ;        // [SZ,5SZ): cols 0..255 q | 256..767 kv/kv2 | 768..1023 q2
    u16* Vt    = ws + 5 * SZ;    // [5SZ,6SZ): Vt -> ypb -> Vt2
    u16* arena = ws + 6 * SZ;    // weights: wq|wkv|wlq|wproj|wlkv
    u16* wfused = arena;                 // [1024][256]
    u16* wproj  = arena + 262144;
    u16* wlkv   = arena + 327680;

    k_f2bf5<<<448, 256, 0, stream>>>(q_w, kv_w, lq_w, proj_w, lkv_w, arena);
    k_transpose_x<<<dim3(32, 8, B_), dim3(32, 8), 0, stream>>>(x, xf);
    // fused q|kv|q2 projections
    k_gemm_bf16<<<dim3(8, 128), 256, 0, stream>>>(xf, wfused, lq_b, 768, qkv, 1024, 1024);
    k_transposeV<<<dim3(32, 8, B_), dim3(32, 8), 0, stream>>>(qkv + 512, 1024, Vt);
    k_attn_mfma<0><<<512, 256, 0, stream>>>(qkv, 1024, qkv + 256, 1024, Vt, xf /*yb*/);
    k_gemm_bf16<<<dim3(2, 128), 256, 0, stream>>>(xf /*yb*/, wproj, proj_b, 0,
                                                  Vt /*ypb*/, 256, 256);
    k_dwconv_add<<<dim3(N_, B_), 256, 0, stream>>>(Vt /*ypb*/, dw_w, dw_b, xf /*s2in*/);
    k_gemm_bf16<<<dim3(4, 128), 256, 0, stream>>>(xf /*s2in*/, wlkv, lkv_b, 0,
                                                  qkv + 256, 512, 1024);
    k_transposeV<<<dim3(32, 8, B_), dim3(32, 8), 0, stream>>>(qkv + 512, 1024, Vt /*Vt2*/);
    k_attn_mfma<1><<<512, 256, 0, stream>>>(qkv + 768, 1024, qkv + 256, 1024, Vt, d_out);
}